// Round 1
// baseline (229.738 us; speedup 1.0000x reference)
//
#include <hip/hip_runtime.h>
#include <stdint.h>

typedef unsigned short u16;
typedef unsigned int u32;
typedef __attribute__((ext_vector_type(8))) short short8;
typedef __attribute__((ext_vector_type(4))) float f32x4;
typedef __attribute__((ext_vector_type(8))) unsigned short u16x8;
typedef __attribute__((ext_vector_type(4))) float float4_t;

__device__ __forceinline__ float b2f(u16 u) { return __uint_as_float(((u32)u) << 16); }
__device__ __forceinline__ u16 f2b(float f) {
  u32 u = __float_as_uint(f);
  u += 0x7fffu + ((u >> 16) & 1u);
  return (u16)(u >> 16);
}

typedef const __attribute__((address_space(1))) void* gas_t;
typedef __attribute__((address_space(3))) void* las_t;
__device__ __forceinline__ void gl_lds16(const void* g, void* l) {
  // LDS dest is wave-uniform base + lane*16; our addressing is linear so this holds.
  __builtin_amdgcn_global_load_lds((gas_t)(uintptr_t)g, (las_t)(u32)(uintptr_t)l, 16, 0, 0);
}

// ---------------- fp32 -> bf16 convert (vectorized) ----------------
__global__ __launch_bounds__(256) void cvt_f2b_kernel(const float* __restrict__ src,
                                                      u16* __restrict__ dst, long n) {
  long i = ((long)blockIdx.x * 256 + threadIdx.x) * 8;
  if (i >= n) return;
  float4_t v0 = *(const float4_t*)(src + i);
  float4_t v1 = *(const float4_t*)(src + i + 4);
  u16x8 o;
#pragma unroll
  for (int j = 0; j < 4; ++j) { o[j] = f2b(v0[j]); o[4 + j] = f2b(v1[j]); }
  *(u16x8*)(dst + i) = o;
}

// ------------- fp32 [R][C] -> bf16 [C][R] transpose+convert -------------
__global__ __launch_bounds__(256) void tr_cvt(const float* __restrict__ src,
                                              u16* __restrict__ dst, int R, int C) {
  __shared__ float t[32][33];
  const int bx = blockIdx.x * 32;  // col base (C dim)
  const int by = blockIdx.y * 32;  // row base (R dim)
  const int tx = threadIdx.x & 31, ty = threadIdx.x >> 5;
#pragma unroll
  for (int i = 0; i < 32; i += 8)
    t[ty + i][tx] = src[(long)(by + ty + i) * C + bx + tx];
  __syncthreads();
#pragma unroll
  for (int i = 0; i < 32; i += 8)
    dst[(long)(bx + ty + i) * R + by + tx] = f2b(t[tx][ty + i]);
}

// ------------- V slice of qkv [B][N][1536] -> vt [B][512][2048] (bf16) -------------
__global__ __launch_bounds__(256) void tr_v(const u16* __restrict__ qkv, u16* __restrict__ vt) {
  __shared__ u16 t[32][33];
  const int b = blockIdx.z;
  const int r0 = blockIdx.x * 32;  // token rows
  const int d0 = blockIdx.y * 32;  // feature
  const int tx = threadIdx.x & 31, ty = threadIdx.x >> 5;
#pragma unroll
  for (int i = 0; i < 32; i += 8)
    t[ty + i][tx] = qkv[((long)b * 2048 + r0 + ty + i) * 1536 + 1024 + d0 + tx];
  __syncthreads();
#pragma unroll
  for (int i = 0; i < 32; i += 8)
    vt[((long)b * 512 + d0 + ty + i) * 2048 + r0 + tx] = t[tx][ty + i];
}

// ---------------- BT-GEMM: C[M][N] = A[M][K] @ Bt[N][K]^T (bf16 in, f32 acc) ----------------
// 128x128 tile, BK=32, 4 waves (2x2), each wave 64x64 via 4x4 16x16x32 MFMA frags.
template <bool OUT_F32, bool BIAS, bool RES>
__global__ __launch_bounds__(256)
void gemm_bt(const u16* __restrict__ A, const u16* __restrict__ Bt, void* __restrict__ Cv,
             const float* __restrict__ bias, const float* __restrict__ res,
             int K, int lda, int ldb, int ldc,
             long aStride, long bStride, long cStride, float alpha) {
  __shared__ u16 As[128 * 32];
  __shared__ u16 Bs[128 * 32];
  const int tid = threadIdx.x;
  const int wid = tid >> 6, lane = tid & 63;
  const int wm = (wid >> 1) * 64, wn = (wid & 1) * 64;
  const long z = blockIdx.z;
  A += z * aStride;
  Bt += z * bStride;
  const int by = blockIdx.y * 128;  // row tile
  const int bx = blockIdx.x * 128;  // col tile

  f32x4 acc[4][4] = {};

  // staging: per wave, rows [wid*32, wid*32+32); 2 calls of 16 rows each, 16B/lane
  const int srow = wid * 32 + (lane >> 2);
  const int scol = (lane & 3) * 8;  // elems
  const u16* Ag = A + (long)(by + srow) * lda + scol;
  const u16* Bg = Bt + (long)(bx + srow) * ldb + scol;
  u16* Al = &As[srow * 32 + scol];
  u16* Bl = &Bs[srow * 32 + scol];
  const int lr = lane & 15, lg = lane >> 4;
  const int nK = K >> 5;

  for (int kt = 0; kt < nK; ++kt) {
    const int ko = kt * 32;
    gl_lds16(Ag + ko, Al);
    gl_lds16(Ag + (long)16 * lda + ko, Al + 16 * 32);
    gl_lds16(Bg + ko, Bl);
    gl_lds16(Bg + (long)16 * ldb + ko, Bl + 16 * 32);
    __syncthreads();  // drains vmcnt -> LDS tiles ready
    short8 a[4], b[4];
#pragma unroll
    for (int i = 0; i < 4; ++i) {
      a[i] = *(const short8*)&As[(wm + i * 16 + lr) * 32 + lg * 8];
      b[i] = *(const short8*)&Bs[(wn + i * 16 + lr) * 32 + lg * 8];
    }
#pragma unroll
    for (int mi = 0; mi < 4; ++mi)
#pragma unroll
      for (int ni = 0; ni < 4; ++ni)
        acc[mi][ni] = __builtin_amdgcn_mfma_f32_16x16x32_bf16(a[mi], b[ni], acc[mi][ni], 0, 0, 0);
    __syncthreads();  // protect LDS from next iteration's staging
  }

  // epilogue: D layout col=lane&15, row=(lane>>4)*4+j  [m89-verified]
  if constexpr (OUT_F32) {
    float* C = (float*)Cv + z * cStride;
#pragma unroll
    for (int mi = 0; mi < 4; ++mi)
#pragma unroll
      for (int ni = 0; ni < 4; ++ni)
#pragma unroll
        for (int j = 0; j < 4; ++j) {
          const long row = by + wm + mi * 16 + lg * 4 + j;
          const int col = bx + wn + ni * 16 + lr;
          float v = acc[mi][ni][j] * alpha;
          if (BIAS) v += bias[col];
          if (RES) v += res[row * (long)ldc + col];
          C[row * (long)ldc + col] = v;
        }
  } else {
    u16* C = (u16*)Cv + z * cStride;
#pragma unroll
    for (int mi = 0; mi < 4; ++mi)
#pragma unroll
      for (int ni = 0; ni < 4; ++ni)
#pragma unroll
        for (int j = 0; j < 4; ++j) {
          const long row = by + wm + mi * 16 + lg * 4 + j;
          const int col = bx + wn + ni * 16 + lr;
          float v = acc[mi][ni][j] * alpha;
          if (BIAS) v += bias[col];
          C[row * (long)ldc + col] = f2b(v);
        }
  }
}

// ---------------- row softmax, in place, bf16 [rows][2048] ----------------
__global__ __launch_bounds__(256) void softmax_rows(u16* __restrict__ S) {
  const long row = blockIdx.x;
  u16* p = S + row * 2048;
  const int tid = threadIdx.x;
  const int wid = tid >> 6, lane = tid & 63;
  u16x8 v = ((const u16x8*)p)[tid];
  float f[8];
#pragma unroll
  for (int j = 0; j < 8; ++j) f[j] = b2f(v[j]);
  float m = f[0];
#pragma unroll
  for (int j = 1; j < 8; ++j) m = fmaxf(m, f[j]);
#pragma unroll
  for (int off = 32; off; off >>= 1) m = fmaxf(m, __shfl_xor(m, off));
  __shared__ float rmax[4], rsum[4];
  if (lane == 0) rmax[wid] = m;
  __syncthreads();
  m = fmaxf(fmaxf(rmax[0], rmax[1]), fmaxf(rmax[2], rmax[3]));
  float s = 0.f;
#pragma unroll
  for (int j = 0; j < 8; ++j) { f[j] = __expf(f[j] - m); s += f[j]; }
#pragma unroll
  for (int off = 32; off; off >>= 1) s += __shfl_xor(s, off);
  if (lane == 0) rsum[wid] = s;
  __syncthreads();
  s = rsum[0] + rsum[1] + rsum[2] + rsum[3];
  const float inv = 1.0f / s;
  u16x8 o;
#pragma unroll
  for (int j = 0; j < 8; ++j) o[j] = f2b(f[j] * inv);
  ((u16x8*)p)[tid] = o;
}

extern "C" void kernel_launch(void* const* d_in, const int* in_sizes, int n_in,
                              void* d_out, int out_size, void* d_ws, size_t ws_size,
                              hipStream_t stream) {
  const float* x = (const float*)d_in[0];      // [8,2048,512]
  const float* w_qkv = (const float*)d_in[1];  // [512,1536]
  const float* b_qkv = (const float*)d_in[2];  // [1536]
  const float* w_fc = (const float*)d_in[3];   // [512,512]
  const float* b_fc = (const float*)d_in[4];   // [512]
  float* out = (float*)d_out;                  // [8,2048,512] f32

  char* ws = (char*)d_ws;
  const long MT = 16384;  // B*N tokens
  // workspace layout (total ~146 MB)
  u16* xb = (u16*)(ws);                    // 16 MB  [16384][512]   (reused as attn_out later)
  u16* wqkvT = (u16*)(ws + 16777216);      // 1.5 MB [1536][512]
  u16* wfcT = (u16*)(ws + 18350080);       // 0.5 MB [512][512]
  u16* qkv = (u16*)(ws + 18874368);        // 48 MB  [16384][1536]
  u16* vt = (u16*)(ws + 69206016);         // 16 MB  [8][512][2048]
  u16* S = (u16*)(ws + 85983232);          // 64 MB  [8][2048][2048]
  u16* attn = xb;                          // reuse x_bf16 region

  // 1. converts / weight transposes
  cvt_f2b_kernel<<<4096, 256, 0, stream>>>(x, xb, MT * 512);
  tr_cvt<<<dim3(48, 16), 256, 0, stream>>>(w_qkv, wqkvT, 512, 1536);
  tr_cvt<<<dim3(16, 16), 256, 0, stream>>>(w_fc, wfcT, 512, 512);

  // 2. qkv = x @ w_qkv + b_qkv   [16384 x 1536], K=512
  gemm_bt<false, true, false><<<dim3(12, 128, 1), 256, 0, stream>>>(
      xb, wqkvT, qkv, b_qkv, nullptr, 512, 512, 512, 1536, 0, 0, 0, 1.0f);

  // 3. vt[b][d][r] = V
  tr_v<<<dim3(64, 16, 8), 256, 0, stream>>>(qkv, vt);

  // 4. S = Q @ K^T * scale  per batch  [2048 x 2048], K=512
  gemm_bt<false, false, false><<<dim3(16, 16, 8), 256, 0, stream>>>(
      qkv, qkv + 512, S, nullptr, nullptr, 512, 1536, 1536, 2048,
      (long)2048 * 1536, (long)2048 * 1536, (long)2048 * 2048, 0.04419417382415922f);

  // 5. P = softmax(S) rows, in place
  softmax_rows<<<16384, 256, 0, stream>>>(S);

  // 6. attn = P @ V  per batch  [2048 x 512], K=2048  (Bt = vt)
  gemm_bt<false, false, false><<<dim3(4, 16, 8), 256, 0, stream>>>(
      S, vt, attn, nullptr, nullptr, 2048, 2048, 2048, 512,
      (long)2048 * 2048, (long)512 * 2048, (long)2048 * 512, 1.0f);

  // 7. out = attn @ w_fc + b_fc + x   [16384 x 512], K=512, f32 out
  gemm_bt<true, true, true><<<dim3(4, 128, 1), 256, 0, stream>>>(
      attn, wfcT, out, b_fc, x, 512, 512, 512, 512, 0, 0, 0, 1.0f);
}

// Round 2
// 208.505 us; speedup vs baseline: 1.1018x; 1.1018x over previous
//
#include <hip/hip_runtime.h>
#include <stdint.h>

typedef unsigned short u16;
typedef unsigned int u32;
typedef __attribute__((ext_vector_type(8))) short short8;
typedef __attribute__((ext_vector_type(4))) float f32x4;
typedef __attribute__((ext_vector_type(8))) unsigned short u16x8;
typedef __attribute__((ext_vector_type(4))) float float4_t;

__device__ __forceinline__ float b2f(u16 u) { return __uint_as_float(((u32)u) << 16); }
__device__ __forceinline__ u16 f2b(float f) {
  u32 u = __float_as_uint(f);
  u += 0x7fffu + ((u >> 16) & 1u);
  return (u16)(u >> 16);
}

typedef const __attribute__((address_space(1))) void* gas_t;
typedef __attribute__((address_space(3))) void* las_t;
__device__ __forceinline__ void gl_lds16(const void* g, void* l) {
  // LDS dest is wave-uniform base + lane*16; our addressing is linear so this holds.
  __builtin_amdgcn_global_load_lds((gas_t)(uintptr_t)g, (las_t)(u32)(uintptr_t)l, 16, 0, 0);
}

// ---------------- fp32 -> bf16 convert (vectorized) ----------------
__global__ __launch_bounds__(256) void cvt_f2b_kernel(const float* __restrict__ src,
                                                      u16* __restrict__ dst, long n) {
  long i = ((long)blockIdx.x * 256 + threadIdx.x) * 8;
  if (i >= n) return;
  float4_t v0 = *(const float4_t*)(src + i);
  float4_t v1 = *(const float4_t*)(src + i + 4);
  u16x8 o;
#pragma unroll
  for (int j = 0; j < 4; ++j) { o[j] = f2b(v0[j]); o[4 + j] = f2b(v1[j]); }
  *(u16x8*)(dst + i) = o;
}

// ------------- fp32 [R][C] -> bf16 [C][R] transpose+convert -------------
__global__ __launch_bounds__(256) void tr_cvt(const float* __restrict__ src,
                                              u16* __restrict__ dst, int R, int C) {
  __shared__ float t[32][33];
  const int bx = blockIdx.x * 32;  // col base (C dim)
  const int by = blockIdx.y * 32;  // row base (R dim)
  const int tx = threadIdx.x & 31, ty = threadIdx.x >> 5;
#pragma unroll
  for (int i = 0; i < 32; i += 8)
    t[ty + i][tx] = src[(long)(by + ty + i) * C + bx + tx];
  __syncthreads();
#pragma unroll
  for (int i = 0; i < 32; i += 8)
    dst[(long)(bx + ty + i) * R + by + tx] = f2b(t[tx][ty + i]);
}

// ------------- V slice of qkv [B][N][1536] -> vt [B][512][2048] (bf16) -------------
__global__ __launch_bounds__(256) void tr_v(const u16* __restrict__ qkv, u16* __restrict__ vt) {
  __shared__ u16 t[32][33];
  const int b = blockIdx.z;
  const int r0 = blockIdx.x * 32;  // token rows
  const int d0 = blockIdx.y * 32;  // feature
  const int tx = threadIdx.x & 31, ty = threadIdx.x >> 5;
#pragma unroll
  for (int i = 0; i < 32; i += 8)
    t[ty + i][tx] = qkv[((long)b * 2048 + r0 + ty + i) * 1536 + 1024 + d0 + tx];
  __syncthreads();
#pragma unroll
  for (int i = 0; i < 32; i += 8)
    vt[((long)b * 512 + d0 + ty + i) * 2048 + r0 + tx] = t[tx][ty + i];
}

// ---------------- BT-GEMM: C[M][N] = A[M][K] @ Bt[N][K]^T (bf16 in, f32 acc) ----------------
// 128x128 tile, BK=32, 4 waves (2x2), each wave 64x64 via 4x4 16x16x32 MFMA frags.
// Triple-buffered LDS, 2-tile-deep prefetch, counted vmcnt (no vmcnt(0) drain in
// steady state). Raw s_barrier (NOT __syncthreads) so the compiler does not emit
// the vmcnt(0) drain. Race-free: stage(t+2) targets buf[(t+2)%3]; that buffer was
// last read in iteration t-1, whose end-barrier precedes this issue point.
template <bool OUT_F32, bool BIAS, bool RES>
__global__ __launch_bounds__(256)
void gemm_bt(const u16* __restrict__ A, const u16* __restrict__ Bt, void* __restrict__ Cv,
             const float* __restrict__ bias, const float* __restrict__ res,
             int K, int lda, int ldb, int ldc,
             long aStride, long bStride, long cStride, float alpha) {
  __shared__ u16 As[3][128 * 32];
  __shared__ u16 Bs[3][128 * 32];
  const int tid = threadIdx.x;
  const int wid = tid >> 6, lane = tid & 63;
  const int wm = (wid >> 1) * 64, wn = (wid & 1) * 64;
  const long z = blockIdx.z;
  A += z * aStride;
  Bt += z * bStride;
  const int by = blockIdx.y * 128;  // row tile
  const int bx = blockIdx.x * 128;  // col tile

  f32x4 acc[4][4] = {};

  // staging: per wave, rows [wid*32, wid*32+32); 2 calls of 16 rows each, 16B/lane
  const int srow = wid * 32 + (lane >> 2);
  const int scol = (lane & 3) * 8;  // elems
  const u16* Ag0 = A + (long)(by + srow) * lda + scol;
  const u16* Ag1 = Ag0 + (long)16 * lda;
  const u16* Bg0 = Bt + (long)(bx + srow) * ldb + scol;
  const u16* Bg1 = Bg0 + (long)16 * ldb;
  const int sL0 = srow * 32 + scol;
  const int sL1 = sL0 + 16 * 32;
  const int lr = lane & 15, lg = lane >> 4;
  const int nK = K >> 5;  // requires K >= 64 (always true here)

  auto stage = [&](int u, int nb) {
    const long ko = (long)u * 32;
    gl_lds16(Ag0 + ko, &As[nb][sL0]);
    gl_lds16(Ag1 + ko, &As[nb][sL1]);
    gl_lds16(Bg0 + ko, &Bs[nb][sL0]);
    gl_lds16(Bg1 + ko, &Bs[nb][sL1]);
  };

  // prologue: tiles 0 and 1 into buffers 0 and 1
  stage(0, 0);
  stage(1, 1);

  int cur = 0;   // buffer holding tile t
  for (int t = 0; t < nK; ++t) {
    if (t + 2 < nK) {
      int nb = cur + 2; if (nb >= 3) nb -= 3;
      stage(t + 2, nb);
      // tiles t+1, t+2 may stay in flight (8 instrs); tile t must have landed
      asm volatile("s_waitcnt vmcnt(8)" ::: "memory");
    } else if (t + 1 < nK) {
      asm volatile("s_waitcnt vmcnt(4)" ::: "memory");
    } else {
      asm volatile("s_waitcnt vmcnt(0)" ::: "memory");
    }
    __builtin_amdgcn_s_barrier();        // all waves' tile-t data visible
    __builtin_amdgcn_sched_barrier(0);   // pin ds_reads below the barrier

    short8 a[4], b[4];
#pragma unroll
    for (int i = 0; i < 4; ++i) {
      a[i] = *(const short8*)&As[cur][(wm + i * 16 + lr) * 32 + lg * 8];
      b[i] = *(const short8*)&Bs[cur][(wn + i * 16 + lr) * 32 + lg * 8];
    }
#pragma unroll
    for (int mi = 0; mi < 4; ++mi)
#pragma unroll
      for (int ni = 0; ni < 4; ++ni)
        acc[mi][ni] = __builtin_amdgcn_mfma_f32_16x16x32_bf16(a[mi], b[ni], acc[mi][ni], 0, 0, 0);

    __builtin_amdgcn_s_barrier();  // all waves done reading buf[cur] before it is re-staged
    ++cur; if (cur == 3) cur = 0;
  }

  // epilogue: D layout col=lane&15, row=(lane>>4)*4+j  [m89-verified]
  if constexpr (OUT_F32) {
    float* C = (float*)Cv + z * cStride;
#pragma unroll
    for (int mi = 0; mi < 4; ++mi)
#pragma unroll
      for (int ni = 0; ni < 4; ++ni)
#pragma unroll
        for (int j = 0; j < 4; ++j) {
          const long row = by + wm + mi * 16 + lg * 4 + j;
          const int col = bx + wn + ni * 16 + lr;
          float v = acc[mi][ni][j] * alpha;
          if (BIAS) v += bias[col];
          if (RES) v += res[row * (long)ldc + col];
          C[row * (long)ldc + col] = v;
        }
  } else {
    u16* C = (u16*)Cv + z * cStride;
#pragma unroll
    for (int mi = 0; mi < 4; ++mi)
#pragma unroll
      for (int ni = 0; ni < 4; ++ni)
#pragma unroll
        for (int j = 0; j < 4; ++j) {
          const long row = by + wm + mi * 16 + lg * 4 + j;
          const int col = bx + wn + ni * 16 + lr;
          float v = acc[mi][ni][j] * alpha;
          if (BIAS) v += bias[col];
          C[row * (long)ldc + col] = f2b(v);
        }
  }
}

// ---------------- row softmax, in place, bf16 [rows][2048] ----------------
__global__ __launch_bounds__(256) void softmax_rows(u16* __restrict__ S) {
  const long row = blockIdx.x;
  u16* p = S + row * 2048;
  const int tid = threadIdx.x;
  const int wid = tid >> 6, lane = tid & 63;
  u16x8 v = ((const u16x8*)p)[tid];
  float f[8];
#pragma unroll
  for (int j = 0; j < 8; ++j) f[j] = b2f(v[j]);
  float m = f[0];
#pragma unroll
  for (int j = 1; j < 8; ++j) m = fmaxf(m, f[j]);
#pragma unroll
  for (int off = 32; off; off >>= 1) m = fmaxf(m, __shfl_xor(m, off));
  __shared__ float rmax[4], rsum[4];
  if (lane == 0) rmax[wid] = m;
  __syncthreads();
  m = fmaxf(fmaxf(rmax[0], rmax[1]), fmaxf(rmax[2], rmax[3]));
  float s = 0.f;
#pragma unroll
  for (int j = 0; j < 8; ++j) { f[j] = __expf(f[j] - m); s += f[j]; }
#pragma unroll
  for (int off = 32; off; off >>= 1) s += __shfl_xor(s, off);
  if (lane == 0) rsum[wid] = s;
  __syncthreads();
  s = rsum[0] + rsum[1] + rsum[2] + rsum[3];
  const float inv = 1.0f / s;
  u16x8 o;
#pragma unroll
  for (int j = 0; j < 8; ++j) o[j] = f2b(f[j] * inv);
  ((u16x8*)p)[tid] = o;
}

extern "C" void kernel_launch(void* const* d_in, const int* in_sizes, int n_in,
                              void* d_out, int out_size, void* d_ws, size_t ws_size,
                              hipStream_t stream) {
  const float* x = (const float*)d_in[0];      // [8,2048,512]
  const float* w_qkv = (const float*)d_in[1];  // [512,1536]
  const float* b_qkv = (const float*)d_in[2];  // [1536]
  const float* w_fc = (const float*)d_in[3];   // [512,512]
  const float* b_fc = (const float*)d_in[4];   // [512]
  float* out = (float*)d_out;                  // [8,2048,512] f32

  char* ws = (char*)d_ws;
  const long MT = 16384;  // B*N tokens
  // workspace layout (total ~146 MB)
  u16* xb = (u16*)(ws);                    // 16 MB  [16384][512]   (reused as attn_out later)
  u16* wqkvT = (u16*)(ws + 16777216);      // 1.5 MB [1536][512]
  u16* wfcT = (u16*)(ws + 18350080);       // 0.5 MB [512][512]
  u16* qkv = (u16*)(ws + 18874368);        // 48 MB  [16384][1536]
  u16* vt = (u16*)(ws + 69206016);         // 16 MB  [8][512][2048]
  u16* S = (u16*)(ws + 85983232);          // 64 MB  [8][2048][2048]
  u16* attn = xb;                          // reuse x_bf16 region

  // 1. converts / weight transposes
  cvt_f2b_kernel<<<4096, 256, 0, stream>>>(x, xb, MT * 512);
  tr_cvt<<<dim3(48, 16), 256, 0, stream>>>(w_qkv, wqkvT, 512, 1536);
  tr_cvt<<<dim3(16, 16), 256, 0, stream>>>(w_fc, wfcT, 512, 512);

  // 2. qkv = x @ w_qkv + b_qkv   [16384 x 1536], K=512
  gemm_bt<false, true, false><<<dim3(12, 128, 1), 256, 0, stream>>>(
      xb, wqkvT, qkv, b_qkv, nullptr, 512, 512, 512, 1536, 0, 0, 0, 1.0f);

  // 3. vt[b][d][r] = V
  tr_v<<<dim3(64, 16, 8), 256, 0, stream>>>(qkv, vt);

  // 4. S = Q @ K^T * scale  per batch  [2048 x 2048], K=512
  gemm_bt<false, false, false><<<dim3(16, 16, 8), 256, 0, stream>>>(
      qkv, qkv + 512, S, nullptr, nullptr, 512, 1536, 1536, 2048,
      (long)2048 * 1536, (long)2048 * 1536, (long)2048 * 2048, 0.04419417382415922f);

  // 5. P = softmax(S) rows, in place
  softmax_rows<<<16384, 256, 0, stream>>>(S);

  // 6. attn = P @ V  per batch  [2048 x 512], K=2048  (Bt = vt)
  gemm_bt<false, false, false><<<dim3(4, 16, 8), 256, 0, stream>>>(
      S, vt, attn, nullptr, nullptr, 2048, 2048, 2048, 512,
      (long)2048 * 2048, (long)512 * 2048, (long)2048 * 512, 1.0f);

  // 7. out = attn @ w_fc + b_fc + x   [16384 x 512], K=512, f32 out
  gemm_bt<true, true, true><<<dim3(4, 128, 1), 256, 0, stream>>>(
      attn, wfcT, out, b_fc, x, 512, 512, 512, 512, 0, 0, 0, 1.0f);
}

// Round 3
// 192.486 us; speedup vs baseline: 1.1935x; 1.0832x over previous
//
#include <hip/hip_runtime.h>
#include <stdint.h>

typedef unsigned short u16;
typedef unsigned int u32;
typedef __attribute__((ext_vector_type(8))) short short8;
typedef __attribute__((ext_vector_type(4))) float f32x4;
typedef __attribute__((ext_vector_type(8))) unsigned short u16x8;
typedef __attribute__((ext_vector_type(4))) float float4_t;

__device__ __forceinline__ float b2f(u16 u) { return __uint_as_float(((u32)u) << 16); }
__device__ __forceinline__ u16 f2b(float f) {
  u32 u = __float_as_uint(f);
  u += 0x7fffu + ((u >> 16) & 1u);
  return (u16)(u >> 16);
}

typedef const __attribute__((address_space(1))) void* gas_t;
typedef __attribute__((address_space(3))) void* las_t;
__device__ __forceinline__ void gl_lds16(const void* g, void* l) {
  // LDS dest is wave-uniform base + lane*16; our addressing is linear so this holds.
  __builtin_amdgcn_global_load_lds((gas_t)(uintptr_t)g, (las_t)(u32)(uintptr_t)l, 16, 0, 0);
}

// ---------------- fp32 -> bf16 convert (vectorized) ----------------
__global__ __launch_bounds__(256) void cvt_f2b_kernel(const float* __restrict__ src,
                                                      u16* __restrict__ dst, long n) {
  long i = ((long)blockIdx.x * 256 + threadIdx.x) * 8;
  if (i >= n) return;
  float4_t v0 = *(const float4_t*)(src + i);
  float4_t v1 = *(const float4_t*)(src + i + 4);
  u16x8 o;
#pragma unroll
  for (int j = 0; j < 4; ++j) { o[j] = f2b(v0[j]); o[4 + j] = f2b(v1[j]); }
  *(u16x8*)(dst + i) = o;
}

// ------------- fp32 [R][C] -> bf16 [C][R] transpose+convert -------------
__global__ __launch_bounds__(256) void tr_cvt(const float* __restrict__ src,
                                              u16* __restrict__ dst, int R, int C) {
  __shared__ float t[32][33];
  const int bx = blockIdx.x * 32;  // col base (C dim)
  const int by = blockIdx.y * 32;  // row base (R dim)
  const int tx = threadIdx.x & 31, ty = threadIdx.x >> 5;
#pragma unroll
  for (int i = 0; i < 32; i += 8)
    t[ty + i][tx] = src[(long)(by + ty + i) * C + bx + tx];
  __syncthreads();
#pragma unroll
  for (int i = 0; i < 32; i += 8)
    dst[(long)(bx + ty + i) * R + by + tx] = f2b(t[tx][ty + i]);
}

// ------------- V slice of qkv [B][N][1536] -> vt [B][512][2048] (bf16) -------------
__global__ __launch_bounds__(256) void tr_v(const u16* __restrict__ qkv, u16* __restrict__ vt) {
  __shared__ u16 t[32][33];
  const int b = blockIdx.z;
  const int r0 = blockIdx.x * 32;  // token rows
  const int d0 = blockIdx.y * 32;  // feature
  const int tx = threadIdx.x & 31, ty = threadIdx.x >> 5;
#pragma unroll
  for (int i = 0; i < 32; i += 8)
    t[ty + i][tx] = qkv[((long)b * 2048 + r0 + ty + i) * 1536 + 1024 + d0 + tx];
  __syncthreads();
#pragma unroll
  for (int i = 0; i < 32; i += 8)
    vt[((long)b * 512 + d0 + ty + i) * 2048 + r0 + tx] = t[tx][ty + i];
}

// ---------------- BT-GEMM: C[M][N] = A[M][K] @ Bt[N][K]^T (bf16 in, f32 acc) ----------------
// 128x128 tile, BK=32, 4 waves (2x2), each wave 64x64 via 4x4 16x16x32 MFMA frags.
// Triple-buffered LDS, 2-tile-deep prefetch, counted vmcnt. Raw s_barrier.
// LDS k-slot swizzle (rule #21 both-sides): global SOURCE col-slot pre-swizzled
// by ((srow>>1)&3); ds_read slot XORed by ((row>>1)&3). Makes every 8-lane
// b128 group a full bank-quad permutation (zero extra conflicts).
// XCD-aware block remap (T1, bijective: all grids %8==0).
template <bool OUT_F32, bool BIAS, bool RES>
__global__ __launch_bounds__(256)
void gemm_bt(const u16* __restrict__ A, const u16* __restrict__ Bt, void* __restrict__ Cv,
             const float* __restrict__ bias, const float* __restrict__ res,
             int K, int lda, int ldb, int ldc,
             long aStride, long bStride, long cStride, float alpha) {
  __shared__ u16 As[3][128 * 32];
  __shared__ u16 Bs[3][128 * 32];
  const int tid = threadIdx.x;
  const int wid = tid >> 6, lane = tid & 63;
  const int wm = (wid >> 1) * 64, wn = (wid & 1) * 64;

  // T1: XCD-aware bijective remap of the flat block id (x-fastest flattening).
  const int gx = gridDim.x, gy = gridDim.y;
  int id = (blockIdx.z * gy + blockIdx.y) * gx + blockIdx.x;
  const int nwg = gx * gy * gridDim.z;  // all call sites have nwg % 8 == 0
  id = (id & 7) * (nwg >> 3) + (id >> 3);
  const int bxi = id % gx;
  const int t2 = id / gx;
  const int byi = t2 % gy;
  const long z = t2 / gy;

  A += z * aStride;
  Bt += z * bStride;
  const int by = byi * 128;  // row tile
  const int bx = bxi * 128;  // col tile

  f32x4 acc[4][4] = {};

  // staging: per wave, rows [wid*32, wid*32+32); 2 calls of 16 rows each, 16B/lane
  const int srow = wid * 32 + (lane >> 2);
  const int scol_lin = (lane & 3) * 8;                         // linear LDS slot (elems)
  const int scol_src = (((lane & 3) ^ ((lane >> 3) & 3)) * 8); // pre-swizzled global slot
  const u16* Ag0 = A + (long)(by + srow) * lda + scol_src;
  const u16* Ag1 = Ag0 + (long)16 * lda;   // (srow+16)>>1 keeps same &3 -> same swizzle
  const u16* Bg0 = Bt + (long)(bx + srow) * ldb + scol_src;
  const u16* Bg1 = Bg0 + (long)16 * ldb;
  const int sL0 = srow * 32 + scol_lin;
  const int sL1 = sL0 + 16 * 32;
  const int lr = lane & 15, lg = lane >> 4;
  const int swz = ((lr >> 1) & 3) ^ lg;    // read-side k-slot for ALL frag rows
  const int nK = K >> 5;  // requires K >= 64 (always true here)

  auto stage = [&](int u, int nb) {
    const long ko = (long)u * 32;
    gl_lds16(Ag0 + ko, &As[nb][sL0]);
    gl_lds16(Ag1 + ko, &As[nb][sL1]);
    gl_lds16(Bg0 + ko, &Bs[nb][sL0]);
    gl_lds16(Bg1 + ko, &Bs[nb][sL1]);
  };

  // prologue: tiles 0 and 1 into buffers 0 and 1
  stage(0, 0);
  stage(1, 1);

  int cur = 0;   // buffer holding tile t
  for (int t = 0; t < nK; ++t) {
    if (t + 2 < nK) {
      int nb = cur + 2; if (nb >= 3) nb -= 3;
      stage(t + 2, nb);
      // tiles t+1, t+2 may stay in flight (8 instrs); tile t must have landed
      asm volatile("s_waitcnt vmcnt(8)" ::: "memory");
    } else if (t + 1 < nK) {
      asm volatile("s_waitcnt vmcnt(4)" ::: "memory");
    } else {
      asm volatile("s_waitcnt vmcnt(0)" ::: "memory");
    }
    __builtin_amdgcn_s_barrier();        // all waves' tile-t data visible
    __builtin_amdgcn_sched_barrier(0);   // pin ds_reads below the barrier

    short8 a[4], b[4];
#pragma unroll
    for (int i = 0; i < 4; ++i) {
      a[i] = *(const short8*)&As[cur][(wm + i * 16 + lr) * 32 + swz * 8];
      b[i] = *(const short8*)&Bs[cur][(wn + i * 16 + lr) * 32 + swz * 8];
    }
    __builtin_amdgcn_s_setprio(1);
#pragma unroll
    for (int mi = 0; mi < 4; ++mi)
#pragma unroll
      for (int ni = 0; ni < 4; ++ni)
        acc[mi][ni] = __builtin_amdgcn_mfma_f32_16x16x32_bf16(a[mi], b[ni], acc[mi][ni], 0, 0, 0);
    __builtin_amdgcn_s_setprio(0);

    __builtin_amdgcn_s_barrier();  // all waves done reading buf[cur] before it is re-staged
    ++cur; if (cur == 3) cur = 0;
  }

  // epilogue: D layout col=lane&15, row=(lane>>4)*4+j  [m89-verified]
  if constexpr (OUT_F32) {
    float* C = (float*)Cv + z * cStride;
#pragma unroll
    for (int mi = 0; mi < 4; ++mi)
#pragma unroll
      for (int ni = 0; ni < 4; ++ni)
#pragma unroll
        for (int j = 0; j < 4; ++j) {
          const long row = by + wm + mi * 16 + lg * 4 + j;
          const int col = bx + wn + ni * 16 + lr;
          float v = acc[mi][ni][j] * alpha;
          if (BIAS) v += bias[col];
          if (RES) v += res[row * (long)ldc + col];
          C[row * (long)ldc + col] = v;
        }
  } else {
    u16* C = (u16*)Cv + z * cStride;
#pragma unroll
    for (int mi = 0; mi < 4; ++mi)
#pragma unroll
      for (int ni = 0; ni < 4; ++ni)
#pragma unroll
        for (int j = 0; j < 4; ++j) {
          const long row = by + wm + mi * 16 + lg * 4 + j;
          const int col = bx + wn + ni * 16 + lr;
          float v = acc[mi][ni][j] * alpha;
          if (BIAS) v += bias[col];
          C[row * (long)ldc + col] = f2b(v);
        }
  }
}

// ---------------- row softmax, in place, bf16 [rows][2048] ----------------
__global__ __launch_bounds__(256) void softmax_rows(u16* __restrict__ S) {
  const long row = blockIdx.x;
  u16* p = S + row * 2048;
  const int tid = threadIdx.x;
  const int wid = tid >> 6, lane = tid & 63;
  u16x8 v = ((const u16x8*)p)[tid];
  float f[8];
#pragma unroll
  for (int j = 0; j < 8; ++j) f[j] = b2f(v[j]);
  float m = f[0];
#pragma unroll
  for (int j = 1; j < 8; ++j) m = fmaxf(m, f[j]);
#pragma unroll
  for (int off = 32; off; off >>= 1) m = fmaxf(m, __shfl_xor(m, off));
  __shared__ float rmax[4], rsum[4];
  if (lane == 0) rmax[wid] = m;
  __syncthreads();
  m = fmaxf(fmaxf(rmax[0], rmax[1]), fmaxf(rmax[2], rmax[3]));
  float s = 0.f;
#pragma unroll
  for (int j = 0; j < 8; ++j) { f[j] = __expf(f[j] - m); s += f[j]; }
#pragma unroll
  for (int off = 32; off; off >>= 1) s += __shfl_xor(s, off);
  if (lane == 0) rsum[wid] = s;
  __syncthreads();
  s = rsum[0] + rsum[1] + rsum[2] + rsum[3];
  const float inv = 1.0f / s;
  u16x8 o;
#pragma unroll
  for (int j = 0; j < 8; ++j) o[j] = f2b(f[j] * inv);
  ((u16x8*)p)[tid] = o;
}

extern "C" void kernel_launch(void* const* d_in, const int* in_sizes, int n_in,
                              void* d_out, int out_size, void* d_ws, size_t ws_size,
                              hipStream_t stream) {
  const float* x = (const float*)d_in[0];      // [8,2048,512]
  const float* w_qkv = (const float*)d_in[1];  // [512,1536]
  const float* b_qkv = (const float*)d_in[2];  // [1536]
  const float* w_fc = (const float*)d_in[3];   // [512,512]
  const float* b_fc = (const float*)d_in[4];   // [512]
  float* out = (float*)d_out;                  // [8,2048,512] f32

  char* ws = (char*)d_ws;
  const long MT = 16384;  // B*N tokens
  // workspace layout (total ~146 MB)
  u16* xb = (u16*)(ws);                    // 16 MB  [16384][512]   (reused as attn_out later)
  u16* wqkvT = (u16*)(ws + 16777216);      // 1.5 MB [1536][512]
  u16* wfcT = (u16*)(ws + 18350080);       // 0.5 MB [512][512]
  u16* qkv = (u16*)(ws + 18874368);        // 48 MB  [16384][1536]
  u16* vt = (u16*)(ws + 69206016);         // 16 MB  [8][512][2048]
  u16* S = (u16*)(ws + 85983232);          // 64 MB  [8][2048][2048]
  u16* attn = xb;                          // reuse x_bf16 region

  // 1. converts / weight transposes
  cvt_f2b_kernel<<<4096, 256, 0, stream>>>(x, xb, MT * 512);
  tr_cvt<<<dim3(48, 16), 256, 0, stream>>>(w_qkv, wqkvT, 512, 1536);
  tr_cvt<<<dim3(16, 16), 256, 0, stream>>>(w_fc, wfcT, 512, 512);

  // 2. qkv = x @ w_qkv + b_qkv   [16384 x 1536], K=512
  gemm_bt<false, true, false><<<dim3(12, 128, 1), 256, 0, stream>>>(
      xb, wqkvT, qkv, b_qkv, nullptr, 512, 512, 512, 1536, 0, 0, 0, 1.0f);

  // 3. vt[b][d][r] = V
  tr_v<<<dim3(64, 16, 8), 256, 0, stream>>>(qkv, vt);

  // 4. S = Q @ K^T * scale  per batch  [2048 x 2048], K=512
  gemm_bt<false, false, false><<<dim3(16, 16, 8), 256, 0, stream>>>(
      qkv, qkv + 512, S, nullptr, nullptr, 512, 1536, 1536, 2048,
      (long)2048 * 1536, (long)2048 * 1536, (long)2048 * 2048, 0.04419417382415922f);

  // 5. P = softmax(S) rows, in place
  softmax_rows<<<16384, 256, 0, stream>>>(S);

  // 6. attn = P @ V  per batch  [2048 x 512], K=2048  (Bt = vt)
  gemm_bt<false, false, false><<<dim3(4, 16, 8), 256, 0, stream>>>(
      S, vt, attn, nullptr, nullptr, 2048, 2048, 2048, 512,
      (long)2048 * 2048, (long)512 * 2048, (long)2048 * 512, 1.0f);

  // 7. out = attn @ w_fc + b_fc + x   [16384 x 512], K=512, f32 out
  gemm_bt<true, true, true><<<dim3(4, 128, 1), 256, 0, stream>>>(
      attn, wfcT, out, b_fc, x, 512, 512, 512, 512, 0, 0, 0, 1.0f);
}

// Round 4
// 190.861 us; speedup vs baseline: 1.2037x; 1.0085x over previous
//
#include <hip/hip_runtime.h>
#include <stdint.h>

typedef unsigned short u16;
typedef unsigned int u32;
typedef __attribute__((ext_vector_type(8))) short short8;
typedef __attribute__((ext_vector_type(4))) float f32x4;
typedef __attribute__((ext_vector_type(8))) unsigned short u16x8;
typedef __attribute__((ext_vector_type(4))) float float4_t;

__device__ __forceinline__ float b2f(u16 u) { return __uint_as_float(((u32)u) << 16); }
__device__ __forceinline__ u16 f2b(float f) {
  u32 u = __float_as_uint(f);
  u += 0x7fffu + ((u >> 16) & 1u);
  return (u16)(u >> 16);
}

typedef const __attribute__((address_space(1))) void* gas_t;
typedef __attribute__((address_space(3))) void* las_t;
__device__ __forceinline__ void gl_lds16(const void* g, void* l) {
  // LDS dest is wave-uniform base + lane*16; our addressing is linear so this holds.
  __builtin_amdgcn_global_load_lds((gas_t)(uintptr_t)g, (las_t)(u32)(uintptr_t)l, 16, 0, 0);
}

// ---------------- fp32 -> bf16 convert (vectorized) ----------------
__global__ __launch_bounds__(256) void cvt_f2b_kernel(const float* __restrict__ src,
                                                      u16* __restrict__ dst, long n) {
  long i = ((long)blockIdx.x * 256 + threadIdx.x) * 8;
  if (i >= n) return;
  float4_t v0 = *(const float4_t*)(src + i);
  float4_t v1 = *(const float4_t*)(src + i + 4);
  u16x8 o;
#pragma unroll
  for (int j = 0; j < 4; ++j) { o[j] = f2b(v0[j]); o[4 + j] = f2b(v1[j]); }
  *(u16x8*)(dst + i) = o;
}

// ------------- fp32 [R][C] -> bf16 [C][R] transpose+convert -------------
__global__ __launch_bounds__(256) void tr_cvt(const float* __restrict__ src,
                                              u16* __restrict__ dst, int R, int C) {
  __shared__ float t[32][33];
  const int bx = blockIdx.x * 32;  // col base (C dim)
  const int by = blockIdx.y * 32;  // row base (R dim)
  const int tx = threadIdx.x & 31, ty = threadIdx.x >> 5;
#pragma unroll
  for (int i = 0; i < 32; i += 8)
    t[ty + i][tx] = src[(long)(by + ty + i) * C + bx + tx];
  __syncthreads();
#pragma unroll
  for (int i = 0; i < 32; i += 8)
    dst[(long)(bx + ty + i) * R + by + tx] = f2b(t[tx][ty + i]);
}

// ------------- V slice of qkv [B][N][1536] -> vt [B][512][2048] (bf16) -------------
__global__ __launch_bounds__(256) void tr_v(const u16* __restrict__ qkv, u16* __restrict__ vt) {
  __shared__ u16 t[32][33];
  const int b = blockIdx.z;
  const int r0 = blockIdx.x * 32;  // token rows
  const int d0 = blockIdx.y * 32;  // feature
  const int tx = threadIdx.x & 31, ty = threadIdx.x >> 5;
#pragma unroll
  for (int i = 0; i < 32; i += 8)
    t[ty + i][tx] = qkv[((long)b * 2048 + r0 + ty + i) * 1536 + 1024 + d0 + tx];
  __syncthreads();
#pragma unroll
  for (int i = 0; i < 32; i += 8)
    vt[((long)b * 512 + d0 + ty + i) * 2048 + r0 + tx] = t[tx][ty + i];
}

// ---------------- BT-GEMM: C[M][N] = A[M][K] @ Bt[N][K]^T (bf16 in, f32 acc) ----------------
// 128x128 tile, BK=32, 4 waves (2x2), each wave 64x64 via 4x4 16x16x32 MFMA frags.
// Double-buffered LDS (32 KB -> 5 blocks/CU), ONE barrier per K-step, deferred vmcnt:
//   iter t: vmcnt(0) [tile t's 4 loads, issued a full iter ago] ; s_barrier ;
//           issue stage(t+1 -> buf^1) ; ds_read buf[t&1] ; MFMA.
// WAR safe: stage(t+1) targets the buffer read in iter t-1; those reads retired
// before each wave entered this barrier (lgkm wait precedes the MFMAs before it).
// RAW safe: every wave vmcnt(0)s its tile-t loads before the barrier.
// LDS k-slot swizzle (both-sides): source col-slot ^((srow>>1)&3), read slot ^((lr>>1)&3)^lg.
// XCD-aware bijective block remap (all grids %8==0).
template <bool OUT_F32, bool BIAS, bool RES>
__global__ __launch_bounds__(256)
void gemm_bt(const u16* __restrict__ A, const u16* __restrict__ Bt, void* __restrict__ Cv,
             const float* __restrict__ bias, const float* __restrict__ res,
             int K, int lda, int ldb, int ldc,
             long aStride, long bStride, long cStride, float alpha) {
  __shared__ u16 As[2][128 * 32];
  __shared__ u16 Bs[2][128 * 32];
  const int tid = threadIdx.x;
  const int wid = tid >> 6, lane = tid & 63;
  const int wm = (wid >> 1) * 64, wn = (wid & 1) * 64;

  // T1: XCD-aware bijective remap of the flat block id (x-fastest flattening).
  const int gx = gridDim.x, gy = gridDim.y;
  int id = (blockIdx.z * gy + blockIdx.y) * gx + blockIdx.x;
  const int nwg = gx * gy * gridDim.z;  // all call sites have nwg % 8 == 0
  id = (id & 7) * (nwg >> 3) + (id >> 3);
  const int bxi = id % gx;
  const int t2 = id / gx;
  const int byi = t2 % gy;
  const long z = t2 / gy;

  A += z * aStride;
  Bt += z * bStride;
  const int by = byi * 128;  // row tile
  const int bx = bxi * 128;  // col tile

  f32x4 acc[4][4] = {};

  // staging: per wave, rows [wid*32, wid*32+32); 2 calls of 16 rows each, 16B/lane
  const int srow = wid * 32 + (lane >> 2);
  const int scol_lin = (lane & 3) * 8;                         // linear LDS slot (elems)
  const int scol_src = (((lane & 3) ^ ((lane >> 3) & 3)) * 8); // pre-swizzled global slot
  const u16* Ag0 = A + (long)(by + srow) * lda + scol_src;
  const u16* Ag1 = Ag0 + (long)16 * lda;   // (srow+16)>>1 keeps same &3 -> same swizzle
  const u16* Bg0 = Bt + (long)(bx + srow) * ldb + scol_src;
  const u16* Bg1 = Bg0 + (long)16 * ldb;
  const int sL0 = srow * 32 + scol_lin;
  const int sL1 = sL0 + 16 * 32;
  const int lr = lane & 15, lg = lane >> 4;
  const int swz = ((lr >> 1) & 3) ^ lg;    // read-side k-slot for ALL frag rows
  const int nK = K >> 5;

  auto stage = [&](int u, int nb) {
    const long ko = (long)u * 32;
    gl_lds16(Ag0 + ko, &As[nb][sL0]);
    gl_lds16(Ag1 + ko, &As[nb][sL1]);
    gl_lds16(Bg0 + ko, &Bs[nb][sL0]);
    gl_lds16(Bg1 + ko, &Bs[nb][sL1]);
  };

  // prologue: tile 0 into buffer 0
  stage(0, 0);

  for (int t = 0; t < nK; ++t) {
    const int cur = t & 1;
    // tile t's loads were issued one full iteration ago -> this wait is cheap.
    asm volatile("s_waitcnt vmcnt(0)" ::: "memory");
    __builtin_amdgcn_s_barrier();        // all waves: tile t visible; prior reads of buf^1 retired
    __builtin_amdgcn_sched_barrier(0);   // pin ds_reads/stages below the barrier
    if (t + 1 < nK) stage(t + 1, cur ^ 1);

    short8 a[4], b[4];
#pragma unroll
    for (int i = 0; i < 4; ++i) {
      a[i] = *(const short8*)&As[cur][(wm + i * 16 + lr) * 32 + swz * 8];
      b[i] = *(const short8*)&Bs[cur][(wn + i * 16 + lr) * 32 + swz * 8];
    }
    __builtin_amdgcn_s_setprio(1);
#pragma unroll
    for (int mi = 0; mi < 4; ++mi)
#pragma unroll
      for (int ni = 0; ni < 4; ++ni)
        acc[mi][ni] = __builtin_amdgcn_mfma_f32_16x16x32_bf16(a[mi], b[ni], acc[mi][ni], 0, 0, 0);
    __builtin_amdgcn_s_setprio(0);
  }

  // epilogue: D layout col=lane&15, row=(lane>>4)*4+j  [m89-verified]
  if constexpr (OUT_F32) {
    float* C = (float*)Cv + z * cStride;
#pragma unroll
    for (int mi = 0; mi < 4; ++mi)
#pragma unroll
      for (int ni = 0; ni < 4; ++ni)
#pragma unroll
        for (int j = 0; j < 4; ++j) {
          const long row = by + wm + mi * 16 + lg * 4 + j;
          const int col = bx + wn + ni * 16 + lr;
          float v = acc[mi][ni][j] * alpha;
          if (BIAS) v += bias[col];
          if (RES) v += res[row * (long)ldc + col];
          C[row * (long)ldc + col] = v;
        }
  } else {
    u16* C = (u16*)Cv + z * cStride;
#pragma unroll
    for (int mi = 0; mi < 4; ++mi)
#pragma unroll
      for (int ni = 0; ni < 4; ++ni)
#pragma unroll
        for (int j = 0; j < 4; ++j) {
          const long row = by + wm + mi * 16 + lg * 4 + j;
          const int col = bx + wn + ni * 16 + lr;
          float v = acc[mi][ni][j] * alpha;
          if (BIAS) v += bias[col];
          C[row * (long)ldc + col] = f2b(v);
        }
  }
}

// ---------------- row softmax, in place, bf16 [rows][2048] ----------------
__global__ __launch_bounds__(256) void softmax_rows(u16* __restrict__ S) {
  const long row = blockIdx.x;
  u16* p = S + row * 2048;
  const int tid = threadIdx.x;
  const int wid = tid >> 6, lane = tid & 63;
  u16x8 v = ((const u16x8*)p)[tid];
  float f[8];
#pragma unroll
  for (int j = 0; j < 8; ++j) f[j] = b2f(v[j]);
  float m = f[0];
#pragma unroll
  for (int j = 1; j < 8; ++j) m = fmaxf(m, f[j]);
#pragma unroll
  for (int off = 32; off; off >>= 1) m = fmaxf(m, __shfl_xor(m, off));
  __shared__ float rmax[4], rsum[4];
  if (lane == 0) rmax[wid] = m;
  __syncthreads();
  m = fmaxf(fmaxf(rmax[0], rmax[1]), fmaxf(rmax[2], rmax[3]));
  float s = 0.f;
#pragma unroll
  for (int j = 0; j < 8; ++j) { f[j] = __expf(f[j] - m); s += f[j]; }
#pragma unroll
  for (int off = 32; off; off >>= 1) s += __shfl_xor(s, off);
  if (lane == 0) rsum[wid] = s;
  __syncthreads();
  s = rsum[0] + rsum[1] + rsum[2] + rsum[3];
  const float inv = 1.0f / s;
  u16x8 o;
#pragma unroll
  for (int j = 0; j < 8; ++j) o[j] = f2b(f[j] * inv);
  ((u16x8*)p)[tid] = o;
}

extern "C" void kernel_launch(void* const* d_in, const int* in_sizes, int n_in,
                              void* d_out, int out_size, void* d_ws, size_t ws_size,
                              hipStream_t stream) {
  const float* x = (const float*)d_in[0];      // [8,2048,512]
  const float* w_qkv = (const float*)d_in[1];  // [512,1536]
  const float* b_qkv = (const float*)d_in[2];  // [1536]
  const float* w_fc = (const float*)d_in[3];   // [512,512]
  const float* b_fc = (const float*)d_in[4];   // [512]
  float* out = (float*)d_out;                  // [8,2048,512] f32

  char* ws = (char*)d_ws;
  const long MT = 16384;  // B*N tokens
  // workspace layout (total ~146 MB)
  u16* xb = (u16*)(ws);                    // 16 MB  [16384][512]   (reused as attn_out later)
  u16* wqkvT = (u16*)(ws + 16777216);      // 1.5 MB [1536][512]
  u16* wfcT = (u16*)(ws + 18350080);       // 0.5 MB [512][512]
  u16* qkv = (u16*)(ws + 18874368);        // 48 MB  [16384][1536]
  u16* vt = (u16*)(ws + 69206016);         // 16 MB  [8][512][2048]
  u16* S = (u16*)(ws + 85983232);          // 64 MB  [8][2048][2048]
  u16* attn = xb;                          // reuse x_bf16 region

  // 1. converts / weight transposes
  cvt_f2b_kernel<<<4096, 256, 0, stream>>>(x, xb, MT * 512);
  tr_cvt<<<dim3(48, 16), 256, 0, stream>>>(w_qkv, wqkvT, 512, 1536);
  tr_cvt<<<dim3(16, 16), 256, 0, stream>>>(w_fc, wfcT, 512, 512);

  // 2. qkv = x @ w_qkv + b_qkv   [16384 x 1536], K=512
  gemm_bt<false, true, false><<<dim3(12, 128, 1), 256, 0, stream>>>(
      xb, wqkvT, qkv, b_qkv, nullptr, 512, 512, 512, 1536, 0, 0, 0, 1.0f);

  // 3. vt[b][d][r] = V
  tr_v<<<dim3(64, 16, 8), 256, 0, stream>>>(qkv, vt);

  // 4. S = Q @ K^T * scale  per batch  [2048 x 2048], K=512
  gemm_bt<false, false, false><<<dim3(16, 16, 8), 256, 0, stream>>>(
      qkv, qkv + 512, S, nullptr, nullptr, 512, 1536, 1536, 2048,
      (long)2048 * 1536, (long)2048 * 1536, (long)2048 * 2048, 0.04419417382415922f);

  // 5. P = softmax(S) rows, in place
  softmax_rows<<<16384, 256, 0, stream>>>(S);

  // 6. attn = P @ V  per batch  [2048 x 512], K=2048  (Bt = vt)
  gemm_bt<false, false, false><<<dim3(4, 16, 8), 256, 0, stream>>>(
      S, vt, attn, nullptr, nullptr, 2048, 2048, 2048, 512,
      (long)2048 * 2048, (long)512 * 2048, (long)2048 * 512, 1.0f);

  // 7. out = attn @ w_fc + b_fc + x   [16384 x 512], K=512, f32 out
  gemm_bt<true, true, true><<<dim3(4, 128, 1), 256, 0, stream>>>(
      attn, wfcT, out, b_fc, x, 512, 512, 512, 512, 0, 0, 0, 1.0f);
}

// Round 6
// 189.058 us; speedup vs baseline: 1.2152x; 1.0095x over previous
//
#include <hip/hip_runtime.h>
#include <stdint.h>

typedef unsigned short u16;
typedef unsigned int u32;
typedef __attribute__((ext_vector_type(8))) short short8;
typedef __attribute__((ext_vector_type(4))) float f32x4;
typedef __attribute__((ext_vector_type(8))) unsigned short u16x8;
typedef __attribute__((ext_vector_type(4))) float float4_t;

__device__ __forceinline__ float b2f(u16 u) { return __uint_as_float(((u32)u) << 16); }
__device__ __forceinline__ u16 f2b(float f) {
  u32 u = __float_as_uint(f);
  u += 0x7fffu + ((u >> 16) & 1u);
  return (u16)(u >> 16);
}

typedef const __attribute__((address_space(1))) void* gas_t;
typedef __attribute__((address_space(3))) void* las_t;
__device__ __forceinline__ void gl_lds16(const void* g, void* l) {
  __builtin_amdgcn_global_load_lds((gas_t)(uintptr_t)g, (las_t)(u32)(uintptr_t)l, 16, 0, 0);
}
__device__ __forceinline__ void barrier_pin() {
  __builtin_amdgcn_sched_barrier(0);
  __builtin_amdgcn_s_barrier();
  __builtin_amdgcn_sched_barrier(0);
}

// ---------------- fp32 -> bf16 convert (vectorized) ----------------
__global__ __launch_bounds__(256) void cvt_f2b_kernel(const float* __restrict__ src,
                                                      u16* __restrict__ dst, long n) {
  long i = ((long)blockIdx.x * 256 + threadIdx.x) * 8;
  if (i >= n) return;
  float4_t v0 = *(const float4_t*)(src + i);
  float4_t v1 = *(const float4_t*)(src + i + 4);
  u16x8 o;
#pragma unroll
  for (int j = 0; j < 4; ++j) { o[j] = f2b(v0[j]); o[4 + j] = f2b(v1[j]); }
  *(u16x8*)(dst + i) = o;
}

// ------------- fp32 [R][C] -> bf16 [C][R] transpose+convert -------------
__global__ __launch_bounds__(256) void tr_cvt(const float* __restrict__ src,
                                              u16* __restrict__ dst, int R, int C) {
  __shared__ float t[32][33];
  const int bx = blockIdx.x * 32;
  const int by = blockIdx.y * 32;
  const int tx = threadIdx.x & 31, ty = threadIdx.x >> 5;
#pragma unroll
  for (int i = 0; i < 32; i += 8)
    t[ty + i][tx] = src[(long)(by + ty + i) * C + bx + tx];
  __syncthreads();
#pragma unroll
  for (int i = 0; i < 32; i += 8)
    dst[(long)(bx + ty + i) * R + by + tx] = f2b(t[tx][ty + i]);
}

// ------------- V slice of qkv [B][N][1536] -> vt [B][512][2048] (bf16) -------------
__global__ __launch_bounds__(256) void tr_v(const u16* __restrict__ qkv, u16* __restrict__ vt) {
  __shared__ u16 t[32][33];
  const int b = blockIdx.z;
  const int r0 = blockIdx.x * 32;
  const int d0 = blockIdx.y * 32;
  const int tx = threadIdx.x & 31, ty = threadIdx.x >> 5;
#pragma unroll
  for (int i = 0; i < 32; i += 8)
    t[ty + i][tx] = qkv[((long)b * 2048 + r0 + ty + i) * 1536 + 1024 + d0 + tx];
  __syncthreads();
#pragma unroll
  for (int i = 0; i < 32; i += 8)
    vt[((long)b * 512 + d0 + ty + i) * 2048 + r0 + tx] = t[tx][ty + i];
}

// ======================= 256-wide 8-phase BT-GEMM =======================
// C[M][N] = A[M][K] @ Bt[N][K]^T.  BM=256, BN=NREP*64, BK=64. 512 thr = 8 waves
// (wr=wid>>2 in {0,1}, wc=wid&3 in {0..3}). 2 K-tiles per loop iter, 8 phases.
//
// INTERLEAVED wave decomposition (required by the stage ledger!):
//   A rows read at phase q (mh=q>>1):  mh*128 + wr*64 + mi*16 + lr  (mi=0..3)
//     -> phase-pair {2h,2h+1} reads EXACTLY stage_A(h)'s rows h*128..h*128+127.
//   NREP=4 B rows at phase q (nh=q&1): nh*128 + wc*32 + ni*16 + lr  (ni=0..1)
//     -> phase nh reads exactly stage_B(nh)'s rows.
//   NREP=2: B=[128][64] single stage half, read at ALL 4 phases (kh=q&1 selects
//   k-half, which is columns -> not stage-splittable).
//
// Stage schedule + hazard ledger (stage issues after prev phase's end barrier;
// "safe" = all readers of that LDS range retired their ds_reads before that
// barrier; same-phase stage/read LDS ranges verified disjoint):
//   p0: A1(T+1)->buf1 [A1-buf1 last read prev p6,p7]  B0(T+1) [prev p4,p6 (N4) / p4-p7 (N2)]
//   p1: B1(T+1) (NREP=4) [prev p5,p7]
//   p2: A0(T+2)->buf0 [read this iter p0,p1]
//   p3: gate vmcnt(2|0): tile T+1 complete (A0 prev p7, A1/B0 p0, B1 p1);
//       younger = A0(T+2) = 2 loads
//   p4: A1(T+2) [read p2,p3]
//   p5: B0(T+2) [N4: read p0,p2; N2: read p0-p3]
//   p6: B1(T+2) (NREP=4) [read p1,p3]
//   p7: A0(T+3)->buf1 [A0-buf1 read p4,p5]; gate vmcnt(2): tile T+2 complete,
//       younger = A0(T+3) = 2 loads
//
// k-slot swizzle (both-sides): LDS row r, 16B-slot s holds global slot s^(r&7)
// (source col pre-swizzled, dest linear: lane l -> global slot (l&7)^(l>>3),
// dest slot l&7, row%8 = l>>3). Reads use slot (ks*4+lg)^(lr&7): 8-lane groups
// hit all 8 bank-quads -> conflict-free b128.
template <int NREP, bool OUT_F32, bool BIAS, bool RES>
__global__ __launch_bounds__(512, 1)
void gemm256(const u16* __restrict__ A, const u16* __restrict__ Bt, void* __restrict__ Cv,
             const float* __restrict__ bias, const float* __restrict__ res,
             int K, int lda, int ldb, int ldc,
             long aStride, long bStride, long cStride, float alpha) {
  __shared__ u16 As[2][256 * 64];
  __shared__ u16 Bs[2][NREP * 64 * 64];
  const int tid = threadIdx.x;
  const int wid = tid >> 6, lane = tid & 63;
  const int wr = wid >> 2, wc = wid & 3;
  const int lr = lane & 15, lg = lane >> 4;

  // XCD-aware bijective remap (all call-site grids have nwg % 8 == 0).
  const int gx = gridDim.x, gy = gridDim.y;
  int id = (blockIdx.z * gy + blockIdx.y) * gx + blockIdx.x;
  const int nwg = gx * gy * gridDim.z;
  id = (id & 7) * (nwg >> 3) + (id >> 3);
  const int bxi = id % gx;
  const int t2 = id / gx;
  const int byi = t2 % gy;
  const long z = t2 / gy;

  A += z * aStride;
  Bt += z * bStride;
  const int by = byi * 256;
  const int bx = bxi * (NREP * 64);

  f32x4 acc[8][NREP] = {};

  // staging geometry
  const int w8l = wid * 8 + (lane >> 3);
  const int scol_src = ((lane & 7) ^ (lane >> 3)) * 8;  // pre-swizzled global slot (elems)
  const int scol_lin = (lane & 7) * 8;                  // linear LDS slot (elems)
  const int nT = K >> 6;

  auto stage_A = [&](int h, int kt) {
    const int bb = kt & 1;
    const long kc = (long)kt * 64 + scol_src;
#pragma unroll
    for (int r = 0; r < 2; ++r) {
      const int row = h * 128 + r * 64 + w8l;
      gl_lds16(A + (long)(by + row) * lda + kc, &As[bb][row * 64 + scol_lin]);
    }
  };
  auto stage_B = [&](int h, int kt) {
    const int bb = kt & 1;
    const long kc = (long)kt * 64 + scol_src;
#pragma unroll
    for (int r = 0; r < 2; ++r) {
      const int row = h * 128 + r * 64 + w8l;
      gl_lds16(Bt + (long)(bx + row) * ldb + kc, &Bs[bb][row * 64 + scol_lin]);
    }
  };

  const int sx = lane & 7;  // read-swizzle key (= row&7 for all frag rows)
  auto do_phase = [&](int bb, int q) {
    if constexpr (NREP == 4) {
      const int mh = q >> 1, nh = q & 1;
      short8 a[4][2], b[2][2];
#pragma unroll
      for (int mi = 0; mi < 4; ++mi)
#pragma unroll
        for (int ks = 0; ks < 2; ++ks)
          a[mi][ks] = *(const short8*)&As[bb][(mh * 128 + wr * 64 + mi * 16 + lr) * 64 +
                                             (((ks * 4 + lg) ^ sx) * 8)];
#pragma unroll
      for (int ni = 0; ni < 2; ++ni)
#pragma unroll
        for (int ks = 0; ks < 2; ++ks)
          b[ni][ks] = *(const short8*)&Bs[bb][(nh * 128 + wc * 32 + ni * 16 + lr) * 64 +
                                             (((ks * 4 + lg) ^ sx) * 8)];
      __builtin_amdgcn_s_setprio(1);
#pragma unroll
      for (int mi = 0; mi < 4; ++mi)
#pragma unroll
        for (int ni = 0; ni < 2; ++ni)
#pragma unroll
          for (int ks = 0; ks < 2; ++ks)
            acc[mh * 4 + mi][nh * 2 + ni] = __builtin_amdgcn_mfma_f32_16x16x32_bf16(
                a[mi][ks], b[ni][ks], acc[mh * 4 + mi][nh * 2 + ni], 0, 0, 0);
      __builtin_amdgcn_s_setprio(0);
    } else {
      const int mh = q >> 1, kh = q & 1;
      short8 a[4], b[2];
#pragma unroll
      for (int mi = 0; mi < 4; ++mi)
        a[mi] = *(const short8*)&As[bb][(mh * 128 + wr * 64 + mi * 16 + lr) * 64 +
                                        (((kh * 4 + lg) ^ sx) * 8)];
#pragma unroll
      for (int ni = 0; ni < 2; ++ni)
        b[ni] = *(const short8*)&Bs[bb][(wc * 32 + ni * 16 + lr) * 64 +
                                        (((kh * 4 + lg) ^ sx) * 8)];
      __builtin_amdgcn_s_setprio(1);
#pragma unroll
      for (int mi = 0; mi < 4; ++mi)
#pragma unroll
        for (int ni = 0; ni < 2; ++ni)
          acc[mh * 4 + mi][ni] = __builtin_amdgcn_mfma_f32_16x16x32_bf16(
              a[mi], b[ni], acc[mh * 4 + mi][ni], 0, 0, 0);
      __builtin_amdgcn_s_setprio(0);
    }
  };

  // -------- prologue: tile 0 fully + A0 of tile 1; wait all but last 2 --------
  stage_A(0, 0); stage_A(1, 0); stage_B(0, 0);
  if constexpr (NREP == 4) stage_B(1, 0);
  stage_A(0, 1);
  asm volatile("s_waitcnt vmcnt(2)" ::: "memory");
  barrier_pin();

  // -------- main loop: 2 K-tiles per iter, 8 phases --------
  for (int T = 0; T < nT; T += 2) {
    const bool more = (T + 2) < nT;  // stages for tiles T+2/T+3 exist
    // p0
    stage_A(1, T + 1); stage_B(0, T + 1);
    do_phase(0, 0);
    barrier_pin();
    // p1
    if constexpr (NREP == 4) stage_B(1, T + 1);
    do_phase(0, 1);
    barrier_pin();
    // p2
    if (more) stage_A(0, T + 2);
    do_phase(0, 2);
    barrier_pin();
    // p3  (gate: tile T+1 fully landed before p4's first reads)
    do_phase(0, 3);
    if (more) asm volatile("s_waitcnt vmcnt(2)" ::: "memory");
    else      asm volatile("s_waitcnt vmcnt(0)" ::: "memory");
    barrier_pin();
    // p4
    if (more) stage_A(1, T + 2);
    do_phase(1, 0);
    barrier_pin();
    // p5
    if (more) stage_B(0, T + 2);
    do_phase(1, 1);
    barrier_pin();
    // p6
    if constexpr (NREP == 4) { if (more) stage_B(1, T + 2); }
    do_phase(1, 2);
    barrier_pin();
    // p7  (gate: tile T+2 fully landed before next iter's p0 reads)
    if (more) stage_A(0, T + 3);  // T+3 < nT whenever T+2 < nT (nT even)
    do_phase(1, 3);
    if (more) asm volatile("s_waitcnt vmcnt(2)" ::: "memory");
    barrier_pin();
  }

  // -------- epilogue: interleaved map; D frag layout col=lane&15, row=lg*4+j --------
  if constexpr (OUT_F32) {
    float* C = (float*)Cv + z * cStride;
#pragma unroll
    for (int mi = 0; mi < 8; ++mi)
#pragma unroll
      for (int ni = 0; ni < NREP; ++ni)
#pragma unroll
        for (int j = 0; j < 4; ++j) {
          const long row = by + (mi >> 2) * 128 + wr * 64 + (mi & 3) * 16 + lg * 4 + j;
          const int col = (NREP == 4)
                              ? bx + (ni >> 1) * 128 + wc * 32 + (ni & 1) * 16 + lr
                              : bx + wc * 32 + ni * 16 + lr;
          float v = acc[mi][ni][j] * alpha;
          if (BIAS) v += bias[col];
          if (RES) v += res[row * (long)ldc + col];
          C[row * (long)ldc + col] = v;
        }
  } else {
    u16* C = (u16*)Cv + z * cStride;
#pragma unroll
    for (int mi = 0; mi < 8; ++mi)
#pragma unroll
      for (int ni = 0; ni < NREP; ++ni)
#pragma unroll
        for (int j = 0; j < 4; ++j) {
          const long row = by + (mi >> 2) * 128 + wr * 64 + (mi & 3) * 16 + lg * 4 + j;
          const int col = (NREP == 4)
                              ? bx + (ni >> 1) * 128 + wc * 32 + (ni & 1) * 16 + lr
                              : bx + wc * 32 + ni * 16 + lr;
          float v = acc[mi][ni][j] * alpha;
          if (BIAS) v += bias[col];
          C[row * (long)ldc + col] = f2b(v);
        }
  }
}

// ---------------- row softmax, in place, bf16 [rows][2048] ----------------
__global__ __launch_bounds__(256) void softmax_rows(u16* __restrict__ S) {
  const long row = blockIdx.x;
  u16* p = S + row * 2048;
  const int tid = threadIdx.x;
  const int wid = tid >> 6, lane = tid & 63;
  u16x8 v = ((const u16x8*)p)[tid];
  float f[8];
#pragma unroll
  for (int j = 0; j < 8; ++j) f[j] = b2f(v[j]);
  float m = f[0];
#pragma unroll
  for (int j = 1; j < 8; ++j) m = fmaxf(m, f[j]);
#pragma unroll
  for (int off = 32; off; off >>= 1) m = fmaxf(m, __shfl_xor(m, off));
  __shared__ float rmax[4], rsum[4];
  if (lane == 0) rmax[wid] = m;
  __syncthreads();
  m = fmaxf(fmaxf(rmax[0], rmax[1]), fmaxf(rmax[2], rmax[3]));
  float s = 0.f;
#pragma unroll
  for (int j = 0; j < 8; ++j) { f[j] = __expf(f[j] - m); s += f[j]; }
#pragma unroll
  for (int off = 32; off; off >>= 1) s += __shfl_xor(s, off);
  if (lane == 0) rsum[wid] = s;
  __syncthreads();
  s = rsum[0] + rsum[1] + rsum[2] + rsum[3];
  const float inv = 1.0f / s;
  u16x8 o;
#pragma unroll
  for (int j = 0; j < 8; ++j) o[j] = f2b(f[j] * inv);
  ((u16x8*)p)[tid] = o;
}

extern "C" void kernel_launch(void* const* d_in, const int* in_sizes, int n_in,
                              void* d_out, int out_size, void* d_ws, size_t ws_size,
                              hipStream_t stream) {
  const float* x = (const float*)d_in[0];      // [8,2048,512]
  const float* w_qkv = (const float*)d_in[1];  // [512,1536]
  const float* b_qkv = (const float*)d_in[2];  // [1536]
  const float* w_fc = (const float*)d_in[3];   // [512,512]
  const float* b_fc = (const float*)d_in[4];   // [512]
  float* out = (float*)d_out;                  // [8,2048,512] f32

  char* ws = (char*)d_ws;
  const long MT = 16384;
  u16* xb = (u16*)(ws);                    // 16 MB  [16384][512]   (reused as attn_out)
  u16* wqkvT = (u16*)(ws + 16777216);      // 1.5 MB [1536][512]
  u16* wfcT = (u16*)(ws + 18350080);       // 0.5 MB [512][512]
  u16* qkv = (u16*)(ws + 18874368);        // 48 MB  [16384][1536]
  u16* vt = (u16*)(ws + 69206016);         // 16 MB  [8][512][2048]
  u16* S = (u16*)(ws + 85983232);          // 64 MB  [8][2048][2048]
  u16* attn = xb;

  cvt_f2b_kernel<<<4096, 256, 0, stream>>>(x, xb, MT * 512);
  tr_cvt<<<dim3(48, 16), 256, 0, stream>>>(w_qkv, wqkvT, 512, 1536);
  tr_cvt<<<dim3(16, 16), 256, 0, stream>>>(w_fc, wfcT, 512, 512);

  // qkv = x @ w_qkv + b_qkv   [16384 x 1536], K=512   (BN=128 -> 768 blocks)
  gemm256<2, false, true, false><<<dim3(12, 64, 1), 512, 0, stream>>>(
      xb, wqkvT, qkv, b_qkv, nullptr, 512, 512, 512, 1536, 0, 0, 0, 1.0f);

  tr_v<<<dim3(64, 16, 8), 256, 0, stream>>>(qkv, vt);

  // S = Q @ K^T * scale  per batch [2048 x 2048], K=512  (BN=256 -> 512 blocks)
  gemm256<4, false, false, false><<<dim3(8, 8, 8), 512, 0, stream>>>(
      qkv, qkv + 512, S, nullptr, nullptr, 512, 1536, 1536, 2048,
      (long)2048 * 1536, (long)2048 * 1536, (long)2048 * 2048, 0.04419417382415922f);

  softmax_rows<<<16384, 256, 0, stream>>>(S);

  // attn = P @ V  per batch [2048 x 512], K=2048  (BN=128 -> 256 blocks)
  gemm256<2, false, false, false><<<dim3(4, 8, 8), 512, 0, stream>>>(
      S, vt, attn, nullptr, nullptr, 2048, 2048, 2048, 512,
      (long)2048 * 2048, (long)512 * 2048, (long)2048 * 512, 1.0f);

  // out = attn @ w_fc + b_fc + x  [16384 x 512], K=512  (BN=128 -> 256 blocks)
  gemm256<2, true, true, true><<<dim3(4, 64, 1), 512, 0, stream>>>(
      attn, wfcT, out, b_fc, x, 512, 512, 512, 512, 0, 0, 0, 1.0f);
}

// Round 7
// 184.391 us; speedup vs baseline: 1.2459x; 1.0253x over previous
//
#include <hip/hip_runtime.h>
#include <stdint.h>

typedef unsigned short u16;
typedef unsigned int u32;
typedef __attribute__((ext_vector_type(8))) short short8;
typedef __attribute__((ext_vector_type(4))) float f32x4;
typedef __attribute__((ext_vector_type(8))) unsigned short u16x8;
typedef __attribute__((ext_vector_type(4))) float float4_t;

__device__ __forceinline__ float b2f(u16 u) { return __uint_as_float(((u32)u) << 16); }
__device__ __forceinline__ u16 f2b(float f) {
  u32 u = __float_as_uint(f);
  u += 0x7fffu + ((u >> 16) & 1u);
  return (u16)(u >> 16);
}

typedef const __attribute__((address_space(1))) void* gas_t;
typedef __attribute__((address_space(3))) void* las_t;
__device__ __forceinline__ void gl_lds16(const void* g, void* l) {
  __builtin_amdgcn_global_load_lds((gas_t)(uintptr_t)g, (las_t)(u32)(uintptr_t)l, 16, 0, 0);
}
__device__ __forceinline__ void barrier_pin() {
  __builtin_amdgcn_sched_barrier(0);
  __builtin_amdgcn_s_barrier();
  __builtin_amdgcn_sched_barrier(0);
}

// ---------------- fp32 -> bf16 convert (vectorized) ----------------
__global__ __launch_bounds__(256) void cvt_f2b_kernel(const float* __restrict__ src,
                                                      u16* __restrict__ dst, long n) {
  long i = ((long)blockIdx.x * 256 + threadIdx.x) * 8;
  if (i >= n) return;
  float4_t v0 = *(const float4_t*)(src + i);
  float4_t v1 = *(const float4_t*)(src + i + 4);
  u16x8 o;
#pragma unroll
  for (int j = 0; j < 4; ++j) { o[j] = f2b(v0[j]); o[4 + j] = f2b(v1[j]); }
  *(u16x8*)(dst + i) = o;
}

// ------------- fp32 [R][C] -> bf16 [C][R] transpose+convert -------------
__global__ __launch_bounds__(256) void tr_cvt(const float* __restrict__ src,
                                              u16* __restrict__ dst, int R, int C) {
  __shared__ float t[32][33];
  const int bx = blockIdx.x * 32;
  const int by = blockIdx.y * 32;
  const int tx = threadIdx.x & 31, ty = threadIdx.x >> 5;
#pragma unroll
  for (int i = 0; i < 32; i += 8)
    t[ty + i][tx] = src[(long)(by + ty + i) * C + bx + tx];
  __syncthreads();
#pragma unroll
  for (int i = 0; i < 32; i += 8)
    dst[(long)(bx + ty + i) * R + by + tx] = f2b(t[tx][ty + i]);
}

// ------------- V slice of qkv [B][N][1536] -> vt [B][512][2048] (bf16) -------------
__global__ __launch_bounds__(256) void tr_v(const u16* __restrict__ qkv, u16* __restrict__ vt) {
  __shared__ u16 t[32][33];
  const int b = blockIdx.z;
  const int r0 = blockIdx.x * 32;
  const int d0 = blockIdx.y * 32;
  const int tx = threadIdx.x & 31, ty = threadIdx.x >> 5;
#pragma unroll
  for (int i = 0; i < 32; i += 8)
    t[ty + i][tx] = qkv[((long)b * 2048 + r0 + ty + i) * 1536 + 1024 + d0 + tx];
  __syncthreads();
#pragma unroll
  for (int i = 0; i < 32; i += 8)
    vt[((long)b * 512 + d0 + ty + i) * 2048 + r0 + tx] = t[tx][ty + i];
}

// ======================= 256-wide 4-phase BT-GEMM =======================
// C[M][N] = A[M][K] @ Bt[N][K]^T.  BM=256, BN=NREP*64, BK=64. 512 thr = 8 waves
// (wr=wid>>2, wc=wid&3). 2 K-tiles (buf0=T even, buf1=T+1) per iter, 4 phases.
// Each fragment is read from LDS exactly ONCE per K-tile: B-frags for the whole
// tile are held in registers (bh[NREP][2], 16/32 VGPR) across the phase pair.
//   P0: reads tile T   (buf0): B-all + A-mh0; 16*NREP/2.. MFMA (mh0 x all n x ks)
//   P1: reads tile T   (buf0): A-mh1        ; MFMA (mh1) using held bh
//   P2/P3: same for tile T+1 (buf1)
// A-read rows: mh*128 + wr*64 + mi*16 + lr  -> A-half mh read ONLY at its phase.
// B-read rows (N4): (n>>1)*128 + wc*32 + (n&1)*16 + lr ; (N2): wc*32 + n*16 + lr.
//
// Stage schedule + hazard ledger (stage issues at phase start, after prev end
// barrier; WAR-safe = all readers of that LDS range retired before that barrier;
// same-phase stage/read ranges verified disjoint):
//   P0: A1(T+1)->buf1 [A1-buf1 last read prev P3]; B(T+1)->buf1 [last read prev P2]
//       (reads buf0 only -> disjoint)
//   P1: A0(T+2)->buf0 [A0-buf0 read P0]; B(T+2)->buf0 [B-buf0 read P0]
//       (P1 reads only As-buf0 rows[128:256) -> disjoint from A0 rows[0:128)/Bs)
//       gate END-P1: vmcnt(6 N4 | 4 N2) = P1's own younger loads -> everything
//       through B(T+1) retired -> tile T+1 complete before P2's first reads.
//       (more=false: vmcnt(0) drain.)
//   P2: A1(T+2)->buf0 [A1-buf0 read P1] (reads buf1 -> disjoint)
//   P3: A0(T+3)->buf1 [A0-buf1 read P2] (P3 reads As-buf1 rows[128:256) -> disjoint)
//       gate END-P3: vmcnt(2) = A0(T+3) -> tile T+2 complete before next P0.
// Loads/tile: A0 2 + A1 2 + B NREP*1.. (N4: 4, N2: 2). nT always even here.
//
// k-slot swizzle (both-sides): LDS row r, 16B-slot s holds global slot s^(r&7)
// (source pre-swizzled, dest linear). Reads use slot (ks*4+lg)^(lr&7) ->
// conflict-free b128. XCD-aware bijective remap (all grids %8==0).
template <int NREP, bool OUT_F32, bool BIAS, bool RES>
__global__ __launch_bounds__(512, 1)
void gemm256(const u16* __restrict__ A, const u16* __restrict__ Bt, void* __restrict__ Cv,
             const float* __restrict__ bias, const float* __restrict__ res,
             int K, int lda, int ldb, int ldc,
             long aStride, long bStride, long cStride, float alpha) {
  __shared__ u16 As[2][256 * 64];
  __shared__ u16 Bs[2][NREP * 64 * 64];
  const int tid = threadIdx.x;
  const int wid = tid >> 6, lane = tid & 63;
  const int wr = wid >> 2, wc = wid & 3;
  const int lr = lane & 15, lg = lane >> 4;

  const int gx = gridDim.x, gy = gridDim.y;
  int id = (blockIdx.z * gy + blockIdx.y) * gx + blockIdx.x;
  const int nwg = gx * gy * gridDim.z;
  id = (id & 7) * (nwg >> 3) + (id >> 3);
  const int bxi = id % gx;
  const int t2 = id / gx;
  const int byi = t2 % gy;
  const long z = t2 / gy;

  A += z * aStride;
  Bt += z * bStride;
  const int by = byi * 256;
  const int bx = bxi * (NREP * 64);

  f32x4 acc[8][NREP] = {};
  short8 bh[NREP][2];  // B-frags held across the tile's phase pair

  const int w8l = wid * 8 + (lane >> 3);
  const int scol_src = ((lane & 7) ^ (lane >> 3)) * 8;
  const int scol_lin = (lane & 7) * 8;
  const int nT = K >> 6;
  const int sx = lane & 7;

  auto stage_A = [&](int h, int kt) {
    const int bb = kt & 1;
    const long kc = (long)kt * 64 + scol_src;
#pragma unroll
    for (int r = 0; r < 2; ++r) {
      const int row = h * 128 + r * 64 + w8l;
      gl_lds16(A + (long)(by + row) * lda + kc, &As[bb][row * 64 + scol_lin]);
    }
  };
  auto stage_Bf = [&](int kt) {  // full B tile (NREP*64 rows)
    const int bb = kt & 1;
    const long kc = (long)kt * 64 + scol_src;
#pragma unroll
    for (int r = 0; r < NREP; ++r) {
      const int row = r * 64 + w8l;
      gl_lds16(Bt + (long)(bx + row) * ldb + kc, &Bs[bb][row * 64 + scol_lin]);
    }
  };

  auto read_B = [&](int bb) {
#pragma unroll
    for (int n = 0; n < NREP; ++n) {
      const int brow = (NREP == 4) ? ((n >> 1) * 128 + wc * 32 + (n & 1) * 16 + lr)
                                   : (wc * 32 + n * 16 + lr);
#pragma unroll
      for (int ks = 0; ks < 2; ++ks)
        bh[n][ks] = *(const short8*)&Bs[bb][brow * 64 + (((ks * 4 + lg) ^ sx) * 8)];
    }
  };
  auto half_mfma = [&](int bb, int mh) {
    short8 a[4][2];
#pragma unroll
    for (int mi = 0; mi < 4; ++mi)
#pragma unroll
      for (int ks = 0; ks < 2; ++ks)
        a[mi][ks] = *(const short8*)&As[bb][(mh * 128 + wr * 64 + mi * 16 + lr) * 64 +
                                            (((ks * 4 + lg) ^ sx) * 8)];
    __builtin_amdgcn_s_setprio(1);
#pragma unroll
    for (int mi = 0; mi < 4; ++mi)
#pragma unroll
      for (int n = 0; n < NREP; ++n)
#pragma unroll
        for (int ks = 0; ks < 2; ++ks)
          acc[mh * 4 + mi][n] = __builtin_amdgcn_mfma_f32_16x16x32_bf16(
              a[mi][ks], bh[n][ks], acc[mh * 4 + mi][n], 0, 0, 0);
    __builtin_amdgcn_s_setprio(0);
  };

  // -------- prologue: tile 0 fully + A0 of tile 1; gate all-but-A0(1) --------
  stage_A(0, 0); stage_A(1, 0); stage_Bf(0);
  stage_A(0, 1);
  asm volatile("s_waitcnt vmcnt(2)" ::: "memory");
  barrier_pin();

  // -------- main loop: 2 K-tiles per iter, 4 phases --------
  for (int T = 0; T < nT; T += 2) {
    const bool more = (T + 2) < nT;
    // P0
    stage_A(1, T + 1); stage_Bf(T + 1);
    read_B(0); half_mfma(0, 0);
    barrier_pin();
    // P1
    if (more) { stage_A(0, T + 2); stage_Bf(T + 2); }
    half_mfma(0, 1);
    if (more) {
      if constexpr (NREP == 4) asm volatile("s_waitcnt vmcnt(6)" ::: "memory");
      else                     asm volatile("s_waitcnt vmcnt(4)" ::: "memory");
    } else {
      asm volatile("s_waitcnt vmcnt(0)" ::: "memory");
    }
    barrier_pin();
    // P2
    if (more) stage_A(1, T + 2);
    read_B(1); half_mfma(1, 0);
    barrier_pin();
    // P3
    if (more) stage_A(0, T + 3);  // T+3 < nT whenever T+2 < nT (nT even)
    half_mfma(1, 1);
    if (more) asm volatile("s_waitcnt vmcnt(2)" ::: "memory");
    barrier_pin();
  }

  // -------- epilogue: interleaved map; D frag layout col=lane&15, row=lg*4+j --------
  if constexpr (OUT_F32) {
    float* C = (float*)Cv + z * cStride;
#pragma unroll
    for (int mi = 0; mi < 8; ++mi)
#pragma unroll
      for (int ni = 0; ni < NREP; ++ni)
#pragma unroll
        for (int j = 0; j < 4; ++j) {
          const long row = by + (mi >> 2) * 128 + wr * 64 + (mi & 3) * 16 + lg * 4 + j;
          const int col = (NREP == 4)
                              ? bx + (ni >> 1) * 128 + wc * 32 + (ni & 1) * 16 + lr
                              : bx + wc * 32 + ni * 16 + lr;
          float v = acc[mi][ni][j] * alpha;
          if (BIAS) v += bias[col];
          if (RES) v += res[row * (long)ldc + col];
          C[row * (long)ldc + col] = v;
        }
  } else {
    u16* C = (u16*)Cv + z * cStride;
#pragma unroll
    for (int mi = 0; mi < 8; ++mi)
#pragma unroll
      for (int ni = 0; ni < NREP; ++ni)
#pragma unroll
        for (int j = 0; j < 4; ++j) {
          const long row = by + (mi >> 2) * 128 + wr * 64 + (mi & 3) * 16 + lg * 4 + j;
          const int col = (NREP == 4)
                              ? bx + (ni >> 1) * 128 + wc * 32 + (ni & 1) * 16 + lr
                              : bx + wc * 32 + ni * 16 + lr;
          float v = acc[mi][ni][j] * alpha;
          if (BIAS) v += bias[col];
          C[row * (long)ldc + col] = f2b(v);
        }
  }
}

// ---------------- row softmax, in place, bf16 [rows][2048] ----------------
__global__ __launch_bounds__(256) void softmax_rows(u16* __restrict__ S) {
  const long row = blockIdx.x;
  u16* p = S + row * 2048;
  const int tid = threadIdx.x;
  const int wid = tid >> 6, lane = tid & 63;
  u16x8 v = ((const u16x8*)p)[tid];
  float f[8];
#pragma unroll
  for (int j = 0; j < 8; ++j) f[j] = b2f(v[j]);
  float m = f[0];
#pragma unroll
  for (int j = 1; j < 8; ++j) m = fmaxf(m, f[j]);
#pragma unroll
  for (int off = 32; off; off >>= 1) m = fmaxf(m, __shfl_xor(m, off));
  __shared__ float rmax[4], rsum[4];
  if (lane == 0) rmax[wid] = m;
  __syncthreads();
  m = fmaxf(fmaxf(rmax[0], rmax[1]), fmaxf(rmax[2], rmax[3]));
  float s = 0.f;
#pragma unroll
  for (int j = 0; j < 8; ++j) { f[j] = __expf(f[j] - m); s += f[j]; }
#pragma unroll
  for (int off = 32; off; off >>= 1) s += __shfl_xor(s, off);
  if (lane == 0) rsum[wid] = s;
  __syncthreads();
  s = rsum[0] + rsum[1] + rsum[2] + rsum[3];
  const float inv = 1.0f / s;
  u16x8 o;
#pragma unroll
  for (int j = 0; j < 8; ++j) o[j] = f2b(f[j] * inv);
  ((u16x8*)p)[tid] = o;
}

extern "C" void kernel_launch(void* const* d_in, const int* in_sizes, int n_in,
                              void* d_out, int out_size, void* d_ws, size_t ws_size,
                              hipStream_t stream) {
  const float* x = (const float*)d_in[0];      // [8,2048,512]
  const float* w_qkv = (const float*)d_in[1];  // [512,1536]
  const float* b_qkv = (const float*)d_in[2];  // [1536]
  const float* w_fc = (const float*)d_in[3];   // [512,512]
  const float* b_fc = (const float*)d_in[4];   // [512]
  float* out = (float*)d_out;                  // [8,2048,512] f32

  char* ws = (char*)d_ws;
  const long MT = 16384;
  u16* xb = (u16*)(ws);                    // 16 MB  [16384][512]   (reused as attn_out)
  u16* wqkvT = (u16*)(ws + 16777216);      // 1.5 MB [1536][512]
  u16* wfcT = (u16*)(ws + 18350080);       // 0.5 MB [512][512]
  u16* qkv = (u16*)(ws + 18874368);        // 48 MB  [16384][1536]
  u16* vt = (u16*)(ws + 69206016);         // 16 MB  [8][512][2048]
  u16* S = (u16*)(ws + 85983232);          // 64 MB  [8][2048][2048]
  u16* attn = xb;

  cvt_f2b_kernel<<<4096, 256, 0, stream>>>(x, xb, MT * 512);
  tr_cvt<<<dim3(48, 16), 256, 0, stream>>>(w_qkv, wqkvT, 512, 1536);
  tr_cvt<<<dim3(16, 16), 256, 0, stream>>>(w_fc, wfcT, 512, 512);

  // qkv = x @ w_qkv + b_qkv   [16384 x 1536], K=512   (BN=128 -> 768 blocks)
  gemm256<2, false, true, false><<<dim3(12, 64, 1), 512, 0, stream>>>(
      xb, wqkvT, qkv, b_qkv, nullptr, 512, 512, 512, 1536, 0, 0, 0, 1.0f);

  tr_v<<<dim3(64, 16, 8), 256, 0, stream>>>(qkv, vt);

  // S = Q @ K^T * scale  per batch [2048 x 2048], K=512  (BN=256 -> 512 blocks)
  gemm256<4, false, false, false><<<dim3(8, 8, 8), 512, 0, stream>>>(
      qkv, qkv + 512, S, nullptr, nullptr, 512, 1536, 1536, 2048,
      (long)2048 * 1536, (long)2048 * 1536, (long)2048 * 2048, 0.04419417382415922f);

  softmax_rows<<<16384, 256, 0, stream>>>(S);

  // attn = P @ V  per batch [2048 x 512], K=2048  (BN=128 -> 256 blocks)
  gemm256<2, false, false, false><<<dim3(4, 8, 8), 512, 0, stream>>>(
      S, vt, attn, nullptr, nullptr, 2048, 2048, 2048, 512,
      (long)2048 * 2048, (long)512 * 2048, (long)2048 * 512, 1.0f);

  // out = attn @ w_fc + b_fc + x  [16384 x 512], K=512  (BN=128 -> 256 blocks)
  gemm256<2, true, true, true><<<dim3(4, 64, 1), 512, 0, stream>>>(
      attn, wfcT, out, b_fc, x, 512, 512, 512, 512, 0, 0, 0, 1.0f);
}